// Round 2
// baseline (206.718 us; speedup 1.0000x reference)
//
#include <hip/hip_runtime.h>
#include <stdint.h>

#define B_  2
#define S_  768
#define D_  768
#define H_  8
#define DH_ 96

typedef unsigned short ushort_t;
typedef __bf16 bf16x8 __attribute__((ext_vector_type(8)));
typedef float  f32x4  __attribute__((ext_vector_type(4)));

__device__ inline ushort_t f2bf(float f) {
    union { float f; unsigned int u; } v; v.f = f;
    unsigned int u = v.u;
    unsigned int r = u + 0x7fffu + ((u >> 16) & 1u);
    return (ushort_t)(r >> 16);
}
__device__ inline float bf2f(ushort_t u) {
    union { unsigned int i; float f; } c; c.i = ((unsigned int)u) << 16;
    return c.f;
}

// async global->LDS, 16B per lane; LDS dest is wave-uniform base + lane*16
__device__ inline void glds16(const void* gp, void* lp) {
    auto g = reinterpret_cast<const __attribute__((address_space(1))) uint32_t*>(
        reinterpret_cast<uintptr_t>(gp));
    auto l = reinterpret_cast<__attribute__((address_space(3))) uint32_t*>(
        reinterpret_cast<uintptr_t>(lp));
    __builtin_amdgcn_global_load_lds(g, l, 16, 0, 0);
}

// ---------------------------------------------------------------- convert
__global__ __launch_bounds__(256) void k_convert(
        const float* __restrict__ X, const float* __restrict__ Wq,
        const float* __restrict__ Wk, const float* __restrict__ Wv,
        const float* __restrict__ Wo,
        ushort_t* __restrict__ Xb, ushort_t* __restrict__ Wb) {
    const int NX4 = (B_ * S_ * D_) / 4;   // 294912
    const int NW4 = (D_ * D_) / 4;        // 147456
    int i = blockIdx.x * blockDim.x + threadIdx.x;
    float4 v;
    ushort_t* dst;
    if (i < NX4) {
        v = ((const float4*)X)[i];
        dst = Xb + i * 4;
    } else {
        int wi = i - NX4;
        int sel = wi / NW4;
        int off = wi - sel * NW4;
        const float* src = (sel == 0) ? Wq : (sel == 1) ? Wk : (sel == 2) ? Wv : Wo;
        v = ((const float4*)src)[off];
        dst = Wb + wi * 4;
    }
    ushort4 o;
    o.x = f2bf(v.x); o.y = f2bf(v.y); o.z = f2bf(v.z); o.w = f2bf(v.w);
    *(ushort4*)dst = o;
}

// ---------------------------------------------------------------- 64x64 GEMM, glds staging
// C = A * Bt^T ; A [M,K] bf16 (lda), Bt [N,K] bf16 (ldb). 256 thr = 4 waves 2x2,
// wave does 2x2 mfma 16x16x32. LDS tiles row-major [64][32], no pad (glds layout).
__device__ inline void gemm64_glds(
        const ushort_t* __restrict__ A, int lda,
        const ushort_t* __restrict__ Bt, int ldb,
        int K, int m0, int n0,
        ushort_t* As, ushort_t* Bs, f32x4 acc[2][2]) {
    const int tid  = threadIdx.x;
    const int lane = tid & 63, wave = tid >> 6;
    const int wm = (wave >> 1) * 32, wn = (wave & 1) * 32;
    const int fr = lane & 15, fk = (lane >> 4) * 8;
    const int sr = wave * 16 + (lane >> 2);     // staging row 0..63
    const int sc = (lane & 3) * 8;              // staging col {0,8,16,24}
    const ushort_t* Ap = A  + (size_t)(m0 + sr) * lda + sc;
    const ushort_t* Bp = Bt + (size_t)(n0 + sr) * ldb + sc;
    ushort_t* AsW = As + wave * 512;            // 1024B per wave
    ushort_t* BsW = Bs + wave * 512;
    for (int kt = 0; kt < K; kt += 32) {
        if (kt) __syncthreads();
        glds16(Ap + kt, AsW);
        glds16(Bp + kt, BsW);
        __syncthreads();
        bf16x8 a0 = *(const bf16x8*)&As[(wm      + fr) * 32 + fk];
        bf16x8 a1 = *(const bf16x8*)&As[(wm + 16 + fr) * 32 + fk];
        bf16x8 b0 = *(const bf16x8*)&Bs[(wn      + fr) * 32 + fk];
        bf16x8 b1 = *(const bf16x8*)&Bs[(wn + 16 + fr) * 32 + fk];
        acc[0][0] = __builtin_amdgcn_mfma_f32_16x16x32_bf16(a0, b0, acc[0][0], 0, 0, 0);
        acc[0][1] = __builtin_amdgcn_mfma_f32_16x16x32_bf16(a0, b1, acc[0][1], 0, 0, 0);
        acc[1][0] = __builtin_amdgcn_mfma_f32_16x16x32_bf16(a1, b0, acc[1][0], 0, 0, 0);
        acc[1][1] = __builtin_amdgcn_mfma_f32_16x16x32_bf16(a1, b1, acc[1][1], 0, 0, 0);
    }
}

// ---------------------------------------------------------------- QKV GEMM 128x64
__global__ __launch_bounds__(256) void k_qkv(
        const ushort_t* __restrict__ Xb, const ushort_t* __restrict__ Wb,
        const float* __restrict__ bq, const float* __restrict__ bk,
        const float* __restrict__ bv,
        ushort_t* __restrict__ Qb, ushort_t* __restrict__ Kb,
        ushort_t* __restrict__ Vtb) {
    __shared__ __align__(16) ushort_t As[128 * 32];
    __shared__ __align__(16) ushort_t Bs[64 * 32];
    f32x4 acc[4][2];
    #pragma unroll
    for (int i = 0; i < 4; i++)
        #pragma unroll
        for (int j = 0; j < 2; j++) acc[i][j] = (f32x4){0.f, 0.f, 0.f, 0.f};
    const int tid = threadIdx.x, lane = tid & 63, wave = tid >> 6;
    const int m0 = blockIdx.y * 128, n0 = blockIdx.x * 64;
    const int fr = lane & 15, fk = (lane >> 4) * 8;
    const int wm = (wave >> 1) * 64, wn = (wave & 1) * 32;
    const int sr = lane >> 2, sc = (lane & 3) * 8;
    const ushort_t* Ap0 = Xb + (size_t)(m0 + wave * 32 + sr) * D_ + sc;
    const ushort_t* Ap1 = Ap0 + 16 * D_;
    const ushort_t* Bp  = Wb + (size_t)(n0 + wave * 16 + sr) * D_ + sc;
    ushort_t* AsW0 = As + wave * 1024;
    ushort_t* AsW1 = As + wave * 1024 + 512;
    ushort_t* BsW  = Bs + wave * 512;
    for (int kt = 0; kt < D_; kt += 32) {
        if (kt) __syncthreads();
        glds16(Ap0 + kt, AsW0);
        glds16(Ap1 + kt, AsW1);
        glds16(Bp  + kt, BsW);
        __syncthreads();
        bf16x8 a[4], b[2];
        #pragma unroll
        for (int mi = 0; mi < 4; mi++)
            a[mi] = *(const bf16x8*)&As[(wm + mi * 16 + fr) * 32 + fk];
        #pragma unroll
        for (int ni = 0; ni < 2; ni++)
            b[ni] = *(const bf16x8*)&Bs[(wn + ni * 16 + fr) * 32 + fk];
        #pragma unroll
        for (int mi = 0; mi < 4; mi++)
            #pragma unroll
            for (int ni = 0; ni < 2; ni++)
                acc[mi][ni] = __builtin_amdgcn_mfma_f32_16x16x32_bf16(a[mi], b[ni], acc[mi][ni], 0, 0, 0);
    }
    #pragma unroll
    for (int ni = 0; ni < 2; ni++) {
        int gcol = n0 + wn + ni * 16 + fr;
        int g = gcol / D_, d768 = gcol - g * D_;
        int h = d768 / DH_, d = d768 - h * DH_;
        float bias = (g == 0 ? bq : (g == 1 ? bk : bv))[d768];
        #pragma unroll
        for (int mi = 0; mi < 4; mi++) {
            #pragma unroll
            for (int r = 0; r < 4; r++) {
                int grow = m0 + wm + mi * 16 + (lane >> 4) * 4 + r;
                int bidx = grow / S_, s = grow - bidx * S_;
                ushort_t ob = f2bf(acc[mi][ni][r] + bias);
                int bh = bidx * H_ + h;
                if (g == 0)      Qb[((size_t)bh * S_ + s) * DH_ + d] = ob;
                else if (g == 1) Kb[((size_t)bh * S_ + s) * DH_ + d] = ob;
                else             Vtb[((size_t)bh * DH_ + d) * S_ + s] = ob;
            }
        }
    }
}

// ---------------------------------------------------------------- qcoef
__global__ __launch_bounds__(256) void k_qcoef(
        const ushort_t* __restrict__ Qb,
        const float* __restrict__ Wd, const float* __restrict__ bd,
        const float* __restrict__ Wa, const float* __restrict__ ba,
        float* __restrict__ qcoef) {
    const int wave = threadIdx.x >> 6, lane = threadIdx.x & 63;
    const int row = blockIdx.x * 4 + wave;
    const ushort_t* q = Qb + (size_t)row * DH_;
    float e0 = bf2f(q[lane]);
    float c0 = e0 * Wd[lane];
    float c1 = e0 * Wa[lane];
    float c2 = e0 * (bd[lane] + ba[lane]);
    if (lane < 32) {
        int d = 64 + lane;
        float e1 = bf2f(q[d]);
        c0 += e1 * Wd[d];
        c1 += e1 * Wa[d];
        c2 += e1 * (bd[d] + ba[d]);
    }
    #pragma unroll
    for (int o = 32; o > 0; o >>= 1) {
        c0 += __shfl_down(c0, o);
        c1 += __shfl_down(c1, o);
        c2 += __shfl_down(c2, o);
    }
    if (lane == 0) {
        qcoef[row * 3 + 0] = c0;
        qcoef[row * 3 + 1] = c1;
        qcoef[row * 3 + 2] = c2;
    }
}

// ---------------------------------------------------------------- scores (raw, to ws)
__global__ __launch_bounds__(256) void k_scores(
        const ushort_t* __restrict__ Qb, const ushort_t* __restrict__ Kb,
        const float* __restrict__ qcoef,
        const float* __restrict__ distm, const float* __restrict__ angm,
        const float* __restrict__ mask, float* __restrict__ Sc) {
    __shared__ __align__(16) ushort_t As[64 * 32];
    __shared__ __align__(16) ushort_t Bs[64 * 32];
    f32x4 acc[2][2];
    #pragma unroll
    for (int i = 0; i < 2; i++)
        #pragma unroll
        for (int j = 0; j < 2; j++) acc[i][j] = (f32x4){0.f, 0.f, 0.f, 0.f};
    const int bh = blockIdx.z, b = bh >> 3;
    const ushort_t* A  = Qb + (size_t)bh * S_ * DH_;
    const ushort_t* Bt = Kb + (size_t)bh * S_ * DH_;
    const int m0 = blockIdx.y * 64, n0 = blockIdx.x * 64;
    gemm64_glds(A, DH_, Bt, DH_, DH_, m0, n0, As, Bs, acc);
    const int lane = threadIdx.x & 63, wave = threadIdx.x >> 6;
    const int wm = (wave >> 1) * 32, wn = (wave & 1) * 32;
    const float isq = 0.10206207261596577f;   // 1/sqrt(96)
    #pragma unroll
    for (int ni = 0; ni < 2; ni++) {
        int j = n0 + wn + ni * 16 + (lane & 15);
        float mb = (1.0f - mask[b * S_ + j]) * -10000.0f;
        #pragma unroll
        for (int mi = 0; mi < 2; mi++) {
            #pragma unroll
            for (int r = 0; r < 4; r++) {
                int i = m0 + wm + mi * 16 + (lane >> 4) * 4 + r;
                const float* qc = qcoef + ((size_t)bh * S_ + i) * 3;
                float dist = distm[((size_t)b * S_ + i) * S_ + j];
                float ang  = angm [((size_t)b * S_ + i) * S_ + j];
                Sc[((size_t)bh * S_ + i) * S_ + j] =
                    acc[mi][ni][r] * isq + dist * qc[0] + ang * qc[1] + qc[2] + mb;
            }
        }
    }
}

// ---------------------------------------------------------------- fused softmax + P@V
// block = 32 q-rows of one bh. Pass 1: row max + expsum. Pass 2: K-loop staging
// p=exp(s-m) as bf16 (MFMA A), writing p/l (f32) to probs output, accumulating P@V.
__global__ __launch_bounds__(256) void k_attnctx(
        const float* __restrict__ Sc, const ushort_t* __restrict__ Vtb,
        float* __restrict__ probs, ushort_t* __restrict__ Ctxb) {
    const int bh = blockIdx.y, b = bh >> 3, h = bh & 7;
    const int r0 = blockIdx.x * 32;
    const float* S = Sc + ((size_t)bh * S_ + r0) * S_;
    const ushort_t* Vt = Vtb + (size_t)bh * DH_ * S_;
    __shared__ float mrow[32], lrow[32];
    __shared__ __align__(16) ushort_t Ps[32 * 32];
    __shared__ __align__(16) ushort_t Vs[96 * 32];
    const int tid = threadIdx.x, lane = tid & 63, wave = tid >> 6;
    // ---- pass 1: stats
    for (int rr = 0; rr < 8; rr++) {
        int row = wave * 8 + rr;
        const float* sr = S + (size_t)row * S_;
        float4 x0 = ((const float4*)sr)[lane];
        float4 x1 = ((const float4*)sr)[lane + 64];
        float4 x2 = ((const float4*)sr)[lane + 128];
        float mx = fmaxf(fmaxf(fmaxf(x0.x, x0.y), fmaxf(x0.z, x0.w)),
                   fmaxf(fmaxf(fmaxf(x1.x, x1.y), fmaxf(x1.z, x1.w)),
                         fmaxf(fmaxf(x2.x, x2.y), fmaxf(x2.z, x2.w))));
        #pragma unroll
        for (int o = 32; o > 0; o >>= 1) mx = fmaxf(mx, __shfl_down(mx, o));
        mx = __shfl(mx, 0);
        float s = __expf(x0.x - mx) + __expf(x0.y - mx) + __expf(x0.z - mx) + __expf(x0.w - mx)
                + __expf(x1.x - mx) + __expf(x1.y - mx) + __expf(x1.z - mx) + __expf(x1.w - mx)
                + __expf(x2.x - mx) + __expf(x2.y - mx) + __expf(x2.z - mx) + __expf(x2.w - mx);
        #pragma unroll
        for (int o = 32; o > 0; o >>= 1) s += __shfl_down(s, o);
        if (lane == 0) { mrow[row] = mx; lrow[row] = s; }
    }
    __syncthreads();
    // ---- pass 2: K-loop
    const int mrow0 = (wave & 1) * 16;          // wave's row half
    const int nb    = (wave >> 1) * 48;         // wave's col range (3 subtiles)
    const int fr = lane & 15, fk = (lane >> 4) * 8;
    const int prow = tid >> 3, pc = (tid & 7) * 4;     // P staging coords
    const float pm = mrow[prow];
    const float pinvl = 1.0f / lrow[prow];
    f32x4 acc[3];
    #pragma unroll
    for (int i = 0; i < 3; i++) acc[i] = (f32x4){0.f, 0.f, 0.f, 0.f};
    const int vr0 = tid >> 2, vc0 = (tid & 3) * 8;      // V staging (i = tid)
    const int i1 = tid + 256;
    const int vr1 = i1 >> 2, vc1 = (i1 & 3) * 8;        // second V load (i1 < 384)
    for (int kt = 0; kt < S_; kt += 32) {
        if (kt) __syncthreads();
        // stage P tile + write probs
        {
            float4 s4 = *(const float4*)(S + (size_t)prow * S_ + kt + pc);
            float e0 = __expf(s4.x - pm), e1 = __expf(s4.y - pm);
            float e2 = __expf(s4.z - pm), e3 = __expf(s4.w - pm);
            ushort4 pb;
            pb.x = f2bf(e0); pb.y = f2bf(e1); pb.z = f2bf(e2); pb.w = f2bf(e3);
            *(ushort4*)&Ps[prow * 32 + pc] = pb;
            float4 pn = {e0 * pinvl, e1 * pinvl, e2 * pinvl, e3 * pinvl};
            *(float4*)&probs[((size_t)bh * S_ + r0 + prow) * S_ + kt + pc] = pn;
        }
        // stage V tile [96 x 32]
        *(uint4*)&Vs[vr0 * 32 + vc0] = *(const uint4*)(Vt + (size_t)vr0 * S_ + kt + vc0);
        if (i1 < 384)
            *(uint4*)&Vs[vr1 * 32 + vc1] = *(const uint4*)(Vt + (size_t)vr1 * S_ + kt + vc1);
        __syncthreads();
        bf16x8 a = *(const bf16x8*)&Ps[(mrow0 + fr) * 32 + fk];
        #pragma unroll
        for (int ni = 0; ni < 3; ni++) {
            bf16x8 bfr = *(const bf16x8*)&Vs[(nb + ni * 16 + fr) * 32 + fk];
            acc[ni] = __builtin_amdgcn_mfma_f32_16x16x32_bf16(a, bfr, acc[ni], 0, 0, 0);
        }
    }
    // ---- epilogue: O = acc / l
    #pragma unroll
    for (int ni = 0; ni < 3; ni++) {
        int col = nb + ni * 16 + fr;
        #pragma unroll
        for (int r = 0; r < 4; r++) {
            int row = mrow0 + (lane >> 4) * 4 + r;
            float o = acc[ni][r] / lrow[row];
            Ctxb[((size_t)(b * S_ + r0 + row)) * D_ + h * DH_ + col] = f2bf(o);
        }
    }
}

// ---------------------------------------------------------------- out GEMM + bias + residual
__global__ __launch_bounds__(256) void k_out(
        const ushort_t* __restrict__ Ctxb, const ushort_t* __restrict__ Wob,
        const float* __restrict__ bo, const float* __restrict__ hidden,
        float* __restrict__ xbuf) {
    __shared__ __align__(16) ushort_t As[64 * 32];
    __shared__ __align__(16) ushort_t Bs[64 * 32];
    f32x4 acc[2][2];
    #pragma unroll
    for (int i = 0; i < 2; i++)
        #pragma unroll
        for (int j = 0; j < 2; j++) acc[i][j] = (f32x4){0.f, 0.f, 0.f, 0.f};
    const int m0 = blockIdx.y * 64, n0 = blockIdx.x * 64;
    gemm64_glds(Ctxb, D_, Wob, D_, D_, m0, n0, As, Bs, acc);
    const int lane = threadIdx.x & 63, wave = threadIdx.x >> 6;
    const int wm = (wave >> 1) * 32, wn = (wave & 1) * 32;
    #pragma unroll
    for (int ni = 0; ni < 2; ni++) {
        int gcol = n0 + wn + ni * 16 + (lane & 15);
        float bias = bo[gcol];
        #pragma unroll
        for (int mi = 0; mi < 2; mi++) {
            #pragma unroll
            for (int r = 0; r < 4; r++) {
                int grow = m0 + wm + mi * 16 + (lane >> 4) * 4 + r;
                xbuf[(size_t)grow * D_ + gcol] =
                    acc[mi][ni][r] + bias + hidden[(size_t)grow * D_ + gcol];
            }
        }
    }
}

// ---------------------------------------------------------------- LayerNorm
__global__ __launch_bounds__(256) void k_ln(
        const float* __restrict__ xbuf, const float* __restrict__ g,
        const float* __restrict__ bb, float* __restrict__ out) {
    const float* x = xbuf + (size_t)blockIdx.x * D_;
    const int t = threadIdx.x;
    float a0 = x[t], a1 = x[t + 256], a2 = x[t + 512];
    float s = a0 + a1 + a2;
    float ss = a0 * a0 + a1 * a1 + a2 * a2;
    __shared__ float r1[4], r2[4];
    #pragma unroll
    for (int o = 32; o > 0; o >>= 1) { s += __shfl_down(s, o); ss += __shfl_down(ss, o); }
    if ((t & 63) == 0) { r1[t >> 6] = s; r2[t >> 6] = ss; }
    __syncthreads();
    float ts = r1[0] + r1[1] + r1[2] + r1[3];
    float tss = r2[0] + r2[1] + r2[2] + r2[3];
    float mu = ts * (1.0f / D_);
    float var = tss * (1.0f / D_) - mu * mu;
    float rstd = rsqrtf(var + 1e-5f);
    float* o = out + (size_t)blockIdx.x * D_;
    o[t]       = (a0 - mu) * rstd * g[t]       + bb[t];
    o[t + 256] = (a1 - mu) * rstd * g[t + 256] + bb[t + 256];
    o[t + 512] = (a2 - mu) * rstd * g[t + 512] + bb[t + 512];
}

// ---------------------------------------------------------------- launch
extern "C" void kernel_launch(void* const* d_in, const int* in_sizes, int n_in,
                              void* d_out, int out_size, void* d_ws, size_t ws_size,
                              hipStream_t stream) {
    const float* X     = (const float*)d_in[0];
    const float* distm = (const float*)d_in[1];
    const float* angm  = (const float*)d_in[2];
    const float* mask  = (const float*)d_in[3];
    const float* Wq    = (const float*)d_in[4];
    const float* bq    = (const float*)d_in[5];
    const float* Wk    = (const float*)d_in[6];
    const float* bk    = (const float*)d_in[7];
    const float* Wv    = (const float*)d_in[8];
    const float* bv    = (const float*)d_in[9];
    const float* Wd    = (const float*)d_in[10];
    const float* bd    = (const float*)d_in[11];
    const float* Wa    = (const float*)d_in[12];
    const float* ba    = (const float*)d_in[13];
    const float* Wo    = (const float*)d_in[14];
    const float* bo    = (const float*)d_in[15];
    const float* ln_g  = (const float*)d_in[16];
    const float* ln_b  = (const float*)d_in[17];

    float* outp  = (float*)d_out;                        // [B,S,D]
    float* probs = (float*)d_out + (size_t)B_ * S_ * D_; // [B,H,S,S]

    char* ws = (char*)d_ws;
    ushort_t* Xb    = (ushort_t*)(ws + 0);          // 2,359,296 B
    ushort_t* Wb    = (ushort_t*)(ws + 2359296);    // 4,718,592 B
    ushort_t* Qb    = (ushort_t*)(ws + 7077888);    // 2,359,296 B
    ushort_t* Kb    = (ushort_t*)(ws + 9437184);    // 2,359,296 B
    ushort_t* Vtb   = (ushort_t*)(ws + 11796480);   // 2,359,296 B
    ushort_t* Ctxb  = (ushort_t*)(ws + 14155776);   // 2,359,296 B
    float*    qcoef = (float*)   (ws + 16515072);   //   147,456 B
    float*    xbuf  = (float*)   (ws + 16662528);   // 4,718,592 B
    float*    Sc    = (float*)   (ws + 21381120);   // 37,748,736 B raw scores (end ~59 MB)

    k_convert<<<3456, 256, 0, stream>>>(X, Wq, Wk, Wv, Wo, Xb, Wb);
    k_qkv<<<dim3(36, 12), 256, 0, stream>>>(Xb, Wb, bq, bk, bv, Qb, Kb, Vtb);
    k_qcoef<<<3072, 256, 0, stream>>>(Qb, Wd, bd, Wa, ba, qcoef);
    k_scores<<<dim3(12, 12, 16), 256, 0, stream>>>(Qb, Kb, qcoef, distm, angm, mask, Sc);
    k_attnctx<<<dim3(24, 16), 256, 0, stream>>>(Sc, Vtb, probs, Ctxb);
    k_out<<<dim3(12, 24), 256, 0, stream>>>(Ctxb, Wb + (size_t)2304 * 768, bo, X, xbuf);
    k_ln<<<1536, 256, 0, stream>>>(xbuf, ln_g, ln_b, outp);
}